// Round 5
// baseline (230.134 us; speedup 1.0000x reference)
//
#include <hip/hip_runtime.h>

#define M_TOT 32768   // B*T = 64*512
#define T_LEN 512
#define NIN   256
#define NH    1024
#define NOUT  256

typedef __attribute__((ext_vector_type(8))) short bf16x8;
typedef __attribute__((ext_vector_type(4))) float f32x4;
typedef unsigned short u16;

__device__ inline float bf2f(u16 u) {
  union { float f; unsigned int i; } v; v.i = ((unsigned int)u) << 16; return v.f;
}
__device__ inline u16 f2bf(float f) {
  union { float f; unsigned int i; } v; v.f = f;
  unsigned int r = v.i + 0x7FFFu + ((v.i >> 16) & 1u);
  return (u16)(r >> 16);
}

__device__ inline void gload_lds16(const void* g, void* l) {
  __builtin_amdgcn_global_load_lds(
      (const __attribute__((address_space(1))) void*)g,
      (__attribute__((address_space(3))) void*)l, 16, 0, 0);
}

// ---------------- prep: bf16 conversions, WiT transpose, Acat build, zero row ----------------
// INz layout: row 0 = zeros (256), row r>=1 = IN row r-1.  [32769][256] bf16
__global__ void prep(const float* __restrict__ inp, const float* __restrict__ Wi,
                     const float* __restrict__ Wih, const float* __restrict__ Whh,
                     const float* __restrict__ Wo,
                     u16* __restrict__ INz, u16* __restrict__ WiT,
                     u16* __restrict__ Acat, u16* __restrict__ Wib, u16* __restrict__ Wob) {
  const long nINz = 256L + (long)M_TOT * NIN;   // 8,388,864
  const long nWiT = 256L * NH;                  // 262,144
  const long nAc  = 2048L * NH;                 // 2,097,152
  const long nWi  = (long)NH * NIN;             // 262,144
  const long nWo  = (long)NOUT * NH;            // 262,144
  const long total = nINz + nWiT + nAc + nWi + nWo;
  for (long i = (long)blockIdx.x * blockDim.x + threadIdx.x; i < total;
       i += (long)gridDim.x * blockDim.x) {
    long j = i;
    if (j < nINz) { INz[j] = (j < 256) ? (u16)0 : f2bf(inp[j - 256]); continue; }
    j -= nINz;
    if (j < nWiT) {  // WiT[it][h] = Wi[h][it]
      long it = j >> 10, h = j & 1023;
      WiT[j] = f2bf(Wi[h * NIN + it]);
      continue;
    }
    j -= nWiT;
    if (j < nAc) {   // Acat = [W_ih ; 0.98*W_hh]  (2048 x 1024)
      long g = j >> 10, h = j & 1023;
      Acat[j] = (g < NH) ? f2bf(Wih[g * NH + h])
                         : f2bf(0.98f * Whh[(g - NH) * NH + h]);
      continue;
    }
    j -= nAc;
    if (j < nWi) { Wib[j] = f2bf(Wi[j]); continue; }
    j -= nWi;
    Wob[j] = f2bf(Wo[j]);
  }
}

// ---------------- biasvec: b1[g]=bih+bhh+W_ih.bi ; b2[g]=0.98*W_hh.bi ----------------
__global__ __launch_bounds__(256) void biasvec(const float* __restrict__ Wih,
                                               const float* __restrict__ Whh,
                                               const float* __restrict__ bi,
                                               const float* __restrict__ bih,
                                               const float* __restrict__ bhh,
                                               float* __restrict__ bias1,
                                               float* __restrict__ bias2) {
  __shared__ float s1[256], s2[256];
  const int g = blockIdx.x, tid = threadIdx.x;
  float a1 = 0.f, a2 = 0.f;
#pragma unroll
  for (int q = 0; q < 4; q++) {
    int h = tid + q * 256;
    float bv = bi[h];
    a1 += Wih[(size_t)g * NH + h] * bv;
    a2 += Whh[(size_t)g * NH + h] * bv;
  }
  s1[tid] = a1; s2[tid] = a2;
  __syncthreads();
  for (int off = 128; off > 0; off >>= 1) {
    if (tid < off) { s1[tid] += s1[tid + off]; s2[tid] += s2[tid + off]; }
    __syncthreads();
  }
  if (tid == 0) {
    bias1[g] = s1[0] + bih[g] + bhh[g];
    bias2[g] = 0.98f * s2[0];
  }
}

// ---------------- wab: Wab2 = [Wa | Wb] folded weights, M=2048,N=256,K=1024 ----------------
__global__ __launch_bounds__(256) void wab(const u16* __restrict__ Acat,
                                           const u16* __restrict__ WiT,
                                           u16* __restrict__ Wab2) {
  __shared__ __align__(16) u16 As[128 * 32];
  __shared__ __align__(16) u16 Bs[128 * 32];
  const int tid = threadIdx.x;
  const int r0 = blockIdx.x * 128, c0 = blockIdx.y * 128;
  const int lane = tid & 63, wave = tid >> 6;
  const int wm = wave >> 1, wn = wave & 1;
  const int lm = lane & 15, kq = lane >> 4;

  f32x4 acc[4][4] = {};
  for (int k0 = 0; k0 < NH; k0 += 32) {
#pragma unroll
    for (int rr = 0; rr < 2; rr++) {
      int c = tid + rr * 256;
      int row = c >> 2, col = (c & 3) * 8;
      gload_lds16(Acat + (size_t)(r0 + row) * NH + k0 + col, (char*)As + c * 16);
      gload_lds16(WiT + (size_t)(c0 + row) * NH + k0 + col, (char*)Bs + c * 16);
    }
    __syncthreads();
    bf16x8 a[4], b[4];
#pragma unroll
    for (int i = 0; i < 4; i++) {
      a[i] = *(const bf16x8*)&As[(wm * 64 + i * 16 + lm) * 32 + kq * 8];
      b[i] = *(const bf16x8*)&Bs[(wn * 64 + i * 16 + lm) * 32 + kq * 8];
    }
#pragma unroll
    for (int i = 0; i < 4; i++)
#pragma unroll
      for (int jn = 0; jn < 4; jn++)
        acc[i][jn] = __builtin_amdgcn_mfma_f32_16x16x32_bf16(a[i], b[jn], acc[i][jn], 0, 0, 0);
    __syncthreads();
  }
#pragma unroll
  for (int i = 0; i < 4; i++) {
    int grb = r0 + wm * 64 + i * 16 + kq * 4;
#pragma unroll
    for (int jn = 0; jn < 4; jn++) {
      int gc = c0 + wn * 64 + jn * 16 + lm;
#pragma unroll
      for (int j = 0; j < 4; j++) {
        int g = grb + j;
        size_t dst = (g < NH) ? ((size_t)g * 512 + gc)
                              : ((size_t)(g - NH) * 512 + 256 + gc);
        Wab2[dst] = f2bf(acc[i][jn][j]);
      }
    }
  }
}

// ---- fusedN: B-in-registers, A in swizzled LDS (BK=64, st-slot = c8 ^ (row&7)) ----
// accX = IN_t*Wi^T (K=256); accC = IN_t*Wa^T + IN_prev*Wb^T (K=512);
// H = 0.98*(accX+bi) + 0.02*relu(accC + b1 [+ b2 if t!=0]) -> out0 f32
__global__ __launch_bounds__(256) void fusedN(const u16* __restrict__ INz,
                                              const u16* __restrict__ Wab2,
                                              const u16* __restrict__ Wib,
                                              const float* __restrict__ bi,
                                              const float* __restrict__ bias1,
                                              const float* __restrict__ bias2,
                                              float* __restrict__ out0) {
  // A tile: logical [128 rows][64 k] bf16; chunk (row, c8) at phys byte
  // row*128 + ((c8 ^ (row&7))*16). Double-buffered: 2 x 16 KB.
  __shared__ __align__(16) u16 As[2][128 * 64];
  const int tid = threadIdx.x;
  const int r0 = blockIdx.x * 128, c0 = blockIdx.y * 128;
  const int lane = tid & 63, wave = tid >> 6;   // 4 waves
  const int wm = wave >> 1, wn = wave & 1;
  const int lm = lane & 15, kq = lane >> 4;

  // staging geometry: instr i covers phys chunks P = (wave*4+i)*64 + lane
  int srow[4], sc8[4], trow[4], pzrow[4];
#pragma unroll
  for (int i = 0; i < 4; i++) {
    int P = (wave * 4 + i) * 64 + lane;
    srow[i] = P >> 3;                       // phys row == logical row
    sc8[i] = (P & 7) ^ ((P >> 3) & 7);      // logical k-chunk for this phys slot
    trow[i] = r0 + srow[i] + 1;             // IN_t source row in INz
    int pr = r0 + srow[i];
    pzrow[i] = ((pr & (T_LEN - 1)) == 0) ? 0 : pr;  // IN_prev source row
  }

  // stage A tile kt (0..7) into buffer bufi. kt<4: IN_t panel, else IN_prev.
#define STAGE(bufi, kt)                                                          \
  {                                                                              \
    _Pragma("unroll") for (int i = 0; i < 4; i++) {                              \
      const u16* src;                                                            \
      if ((kt) < 4)                                                              \
        src = INz + (size_t)trow[i] * NIN + (kt) * 64 + sc8[i] * 8;              \
      else                                                                       \
        src = INz + (size_t)pzrow[i] * NIN + ((kt) - 4) * 64 + sc8[i] * 8;       \
      gload_lds16(src, (char*)As[bufi] + (wave * 4 + i) * 1024 + lane * 16);     \
    }                                                                            \
  }

  f32x4 accC[4][4] = {};
  f32x4 accX[4][4] = {};

  // B row bases (elements)
  const u16* bCbase = Wab2 + (size_t)(c0 + wn * 64 + lm) * 512;
  const u16* bXbase = Wib + (size_t)(c0 + wn * 64 + lm) * NIN;

  STAGE(0, 0);
  __syncthreads();
  int cur = 0;

#pragma unroll
  for (int t = 0; t < 8; t++) {
    // 1) B fragments for both K-steps of this tile, straight from global (L2).
    //    Issued FIRST so their vmcnt waits don't drain the A prefetch (FIFO).
    bf16x8 bc0[4], bc1[4], bx0[4], bx1[4];
#pragma unroll
    for (int nf = 0; nf < 4; nf++) {
      bc0[nf] = *(const bf16x8*)(bCbase + (size_t)nf * 16 * 512 + t * 64 + kq * 8);
      bc1[nf] = *(const bf16x8*)(bCbase + (size_t)nf * 16 * 512 + t * 64 + 32 + kq * 8);
    }
    if (t < 4) {
#pragma unroll
      for (int nf = 0; nf < 4; nf++) {
        bx0[nf] = *(const bf16x8*)(bXbase + (size_t)nf * 16 * NIN + t * 64 + kq * 8);
        bx1[nf] = *(const bf16x8*)(bXbase + (size_t)nf * 16 * NIN + t * 64 + 32 + kq * 8);
      }
    }
    // 2) prefetch next A tile
    if (t < 7) STAGE(cur ^ 1, t + 1);
    // 3) ds_read A fragments (swizzled) + 4) MFMA
    bf16x8 a0[4], a1[4];
#pragma unroll
    for (int mf = 0; mf < 4; mf++) {
      int row = wm * 64 + mf * 16 + lm;
      int s0 = (0 * 4 + kq) ^ (lm & 7);
      int s1 = (1 * 4 + kq) ^ (lm & 7);
      a0[mf] = *(const bf16x8*)((const char*)As[cur] + row * 128 + s0 * 16);
      a1[mf] = *(const bf16x8*)((const char*)As[cur] + row * 128 + s1 * 16);
    }
#pragma unroll
    for (int mf = 0; mf < 4; mf++)
#pragma unroll
      for (int nf = 0; nf < 4; nf++) {
        accC[mf][nf] = __builtin_amdgcn_mfma_f32_16x16x32_bf16(a0[mf], bc0[nf], accC[mf][nf], 0, 0, 0);
        accC[mf][nf] = __builtin_amdgcn_mfma_f32_16x16x32_bf16(a1[mf], bc1[nf], accC[mf][nf], 0, 0, 0);
      }
    if (t < 4) {
#pragma unroll
      for (int mf = 0; mf < 4; mf++)
#pragma unroll
        for (int nf = 0; nf < 4; nf++) {
          accX[mf][nf] = __builtin_amdgcn_mfma_f32_16x16x32_bf16(a0[mf], bx0[nf], accX[mf][nf], 0, 0, 0);
          accX[mf][nf] = __builtin_amdgcn_mfma_f32_16x16x32_bf16(a1[mf], bx1[nf], accX[mf][nf], 0, 0, 0);
        }
    }
    __syncthreads();
    cur ^= 1;
  }
#undef STAGE

#pragma unroll
  for (int mf = 0; mf < 4; mf++) {
    int grb = r0 + wm * 64 + mf * 16 + kq * 4;
#pragma unroll
    for (int nf = 0; nf < 4; nf++) {
      int gc = c0 + wn * 64 + nf * 16 + lm;
      float b1 = bias1[gc], b2v = bias2[gc], biv = bi[gc];
#pragma unroll
      for (int j = 0; j < 4; j++) {
        int gr = grb + j;
        float bb = b1 + (((gr & (T_LEN - 1)) != 0) ? b2v : 0.0f);
        float cv = fmaxf(accC[mf][nf][j] + bb, 0.0f);
        float x = accX[mf][nf][j] + biv;
        out0[(size_t)gr * NH + gc] = 0.98f * x + 0.02f * cv;
      }
    }
  }
}

// ---------------- GEMM3: OUT = H * Wo^T + bo  (A reg-staged f32->bf16) ----------------
__global__ __launch_bounds__(256) void gemm3(const float* __restrict__ H,
                                             const u16* __restrict__ Wob,
                                             const float* __restrict__ bo,
                                             float* __restrict__ out1) {
  __shared__ __align__(16) u16 As[128 * 32];
  __shared__ __align__(16) u16 Bs[128 * 32];
  const int tid = threadIdx.x;
  const int r0 = blockIdx.x * 128, c0 = blockIdx.y * 128;
  const int lane = tid & 63, wave = tid >> 6;
  const int wm = wave >> 1, wn = wave & 1;
  const int lm = lane & 15, kq = lane >> 4;

  f32x4 acc[4][4] = {};
  for (int k0 = 0; k0 < NH; k0 += 32) {
#pragma unroll
    for (int rr = 0; rr < 2; rr++) {
      int c = tid + rr * 256;
      int row = c >> 2, col = (c & 3) * 8;
      const float* src = H + (size_t)(r0 + row) * NH + k0 + col;
      float4 v0 = *(const float4*)src;
      float4 v1 = *(const float4*)(src + 4);
      union { u16 u[8]; uint4 q; } pk;
      pk.u[0] = f2bf(v0.x); pk.u[1] = f2bf(v0.y); pk.u[2] = f2bf(v0.z); pk.u[3] = f2bf(v0.w);
      pk.u[4] = f2bf(v1.x); pk.u[5] = f2bf(v1.y); pk.u[6] = f2bf(v1.z); pk.u[7] = f2bf(v1.w);
      *(uint4*)((char*)As + c * 16) = pk.q;
      gload_lds16(Wob + (size_t)(c0 + row) * NH + k0 + col, (char*)Bs + c * 16);
    }
    __syncthreads();
    bf16x8 a[4], b[4];
#pragma unroll
    for (int i = 0; i < 4; i++) {
      a[i] = *(const bf16x8*)&As[(wm * 64 + i * 16 + lm) * 32 + kq * 8];
      b[i] = *(const bf16x8*)&Bs[(wn * 64 + i * 16 + lm) * 32 + kq * 8];
    }
#pragma unroll
    for (int i = 0; i < 4; i++)
#pragma unroll
      for (int jn = 0; jn < 4; jn++)
        acc[i][jn] = __builtin_amdgcn_mfma_f32_16x16x32_bf16(a[i], b[jn], acc[i][jn], 0, 0, 0);
    __syncthreads();
  }
#pragma unroll
  for (int i = 0; i < 4; i++) {
    int grb = r0 + wm * 64 + i * 16 + kq * 4;
#pragma unroll
    for (int jn = 0; jn < 4; jn++) {
      int gc = c0 + wn * 64 + jn * 16 + lm;
      float bv = bo[gc];
#pragma unroll
      for (int j = 0; j < 4; j++)
        out1[(size_t)(grb + j) * NOUT + gc] = acc[i][jn][j] + bv;
    }
  }
}

extern "C" void kernel_launch(void* const* d_in, const int* in_sizes, int n_in,
                              void* d_out, int out_size, void* d_ws, size_t ws_size,
                              hipStream_t stream) {
  const float* inp = (const float*)d_in[0];
  const float* Wi  = (const float*)d_in[1];
  const float* bi  = (const float*)d_in[2];
  const float* Wih = (const float*)d_in[3];
  const float* bih = (const float*)d_in[4];
  const float* Whh = (const float*)d_in[5];
  const float* bhh = (const float*)d_in[6];
  const float* Wo  = (const float*)d_in[7];
  const float* bo  = (const float*)d_in[8];

  float* out0 = (float*)d_out;                       // hidden [32768,1024] f32
  float* out1 = out0 + (size_t)M_TOT * NH;           // output [32768,256]  f32

  char* ws = (char*)d_ws;
  u16* Acat = (u16*)ws;                              //  2048 x 1024 bf16 =  4,194,304 B
  u16* WiT  = (u16*)(ws + 4194304);                  //   256 x 1024 bf16 =    524,288 B
  u16* Wab2 = (u16*)(ws + 4718592);                  //  1024 x  512 bf16 =  1,048,576 B
  u16* Wib  = (u16*)(ws + 5767168);                  //  1024 x  256 bf16 =    524,288 B
  u16* Wob  = (u16*)(ws + 6291456);                  //   256 x 1024 bf16 =    524,288 B
  float* bias1 = (float*)(ws + 6815744);             //  1024 f32 = 4096 B
  float* bias2 = (float*)(ws + 6819840);             //  1024 f32 = 4096 B
  // total ws usage: 6,823,936 B
  // INz lives in the out1 region (33.5 MB >= 16.8 MB); dead before gemm3 writes out1.
  u16* INz = (u16*)out1;                             // [1+32768][256] bf16 = 16,777,728 B

  hipLaunchKernelGGL(prep, dim3(2048), dim3(256), 0, stream,
                     inp, Wi, Wih, Whh, Wo, INz, WiT, Acat, Wib, Wob);
  hipLaunchKernelGGL(wab, dim3(16, 2), dim3(256), 0, stream, Acat, WiT, Wab2);
  hipLaunchKernelGGL(biasvec, dim3(1024), dim3(256), 0, stream,
                     Wih, Whh, bi, bih, bhh, bias1, bias2);
  hipLaunchKernelGGL(fusedN, dim3(256, 8), dim3(256), 0, stream,
                     INz, Wab2, Wib, bi, bias1, bias2, out0);
  hipLaunchKernelGGL(gemm3, dim3(256, 2), dim3(256), 0, stream, out0, Wob, bo, out1);
}

// Round 6
// 156.460 us; speedup vs baseline: 1.4709x; 1.4709x over previous
//
#include <hip/hip_runtime.h>

#define M_TOT 32768   // B*T = 64*512
#define T_LEN 512
#define NIN   256
#define NH    1024
#define NOUT  256

typedef __attribute__((ext_vector_type(8))) short bf16x8;
typedef __attribute__((ext_vector_type(4))) float f32x4;
typedef unsigned short u16;

__device__ inline float bf2f(u16 u) {
  union { float f; unsigned int i; } v; v.i = ((unsigned int)u) << 16; return v.f;
}
__device__ inline u16 f2bf(float f) {
  union { float f; unsigned int i; } v; v.f = f;
  unsigned int r = v.i + 0x7FFFu + ((v.i >> 16) & 1u);
  return (u16)(r >> 16);
}

__device__ inline void gload_lds16(const void* g, void* l) {
  __builtin_amdgcn_global_load_lds(
      (const __attribute__((address_space(1))) void*)g,
      (__attribute__((address_space(3))) void*)l, 16, 0, 0);
}

// ---------------- prep: bf16 conversions, WiT transpose, Acat build, zero row ----------------
// INz layout: row 0 = zeros (256), row r>=1 = IN row r-1.  [32769][256] bf16
__global__ void prep(const float* __restrict__ inp, const float* __restrict__ Wi,
                     const float* __restrict__ Wih, const float* __restrict__ Whh,
                     const float* __restrict__ Wo,
                     u16* __restrict__ INz, u16* __restrict__ WiT,
                     u16* __restrict__ Acat, u16* __restrict__ Wib, u16* __restrict__ Wob) {
  const long nINz = 256L + (long)M_TOT * NIN;   // 8,388,864
  const long nWiT = 256L * NH;                  // 262,144
  const long nAc  = 2048L * NH;                 // 2,097,152
  const long nWi  = (long)NH * NIN;             // 262,144
  const long nWo  = (long)NOUT * NH;            // 262,144
  const long total = nINz + nWiT + nAc + nWi + nWo;
  for (long i = (long)blockIdx.x * blockDim.x + threadIdx.x; i < total;
       i += (long)gridDim.x * blockDim.x) {
    long j = i;
    if (j < nINz) { INz[j] = (j < 256) ? (u16)0 : f2bf(inp[j - 256]); continue; }
    j -= nINz;
    if (j < nWiT) {  // WiT[it][h] = Wi[h][it]
      long it = j >> 10, h = j & 1023;
      WiT[j] = f2bf(Wi[h * NIN + it]);
      continue;
    }
    j -= nWiT;
    if (j < nAc) {   // Acat = [W_ih ; 0.98*W_hh]  (2048 x 1024)
      long g = j >> 10, h = j & 1023;
      Acat[j] = (g < NH) ? f2bf(Wih[g * NH + h])
                         : f2bf(0.98f * Whh[(g - NH) * NH + h]);
      continue;
    }
    j -= nAc;
    if (j < nWi) { Wib[j] = f2bf(Wi[j]); continue; }
    j -= nWi;
    Wob[j] = f2bf(Wo[j]);
  }
}

// ---------------- biasvec: b1[g]=bih+bhh+W_ih.bi ; b2[g]=0.98*W_hh.bi ----------------
__global__ __launch_bounds__(256) void biasvec(const float* __restrict__ Wih,
                                               const float* __restrict__ Whh,
                                               const float* __restrict__ bi,
                                               const float* __restrict__ bih,
                                               const float* __restrict__ bhh,
                                               float* __restrict__ bias1,
                                               float* __restrict__ bias2) {
  __shared__ float s1[256], s2[256];
  const int g = blockIdx.x, tid = threadIdx.x;
  float a1 = 0.f, a2 = 0.f;
#pragma unroll
  for (int q = 0; q < 4; q++) {
    int h = tid + q * 256;
    float bv = bi[h];
    a1 += Wih[(size_t)g * NH + h] * bv;
    a2 += Whh[(size_t)g * NH + h] * bv;
  }
  s1[tid] = a1; s2[tid] = a2;
  __syncthreads();
  for (int off = 128; off > 0; off >>= 1) {
    if (tid < off) { s1[tid] += s1[tid + off]; s2[tid] += s2[tid + off]; }
    __syncthreads();
  }
  if (tid == 0) {
    bias1[g] = s1[0] + bih[g] + bhh[g];
    bias2[g] = 0.98f * s2[0];
  }
}

// ---------------- wab: Wab2 = [Wa | Wb] folded weights, M=2048,N=256,K=1024 ----------------
__global__ __launch_bounds__(256) void wab(const u16* __restrict__ Acat,
                                           const u16* __restrict__ WiT,
                                           u16* __restrict__ Wab2) {
  __shared__ __align__(16) u16 As[128 * 32];
  __shared__ __align__(16) u16 Bs[128 * 32];
  const int tid = threadIdx.x;
  const int r0 = blockIdx.x * 128, c0 = blockIdx.y * 128;
  const int lane = tid & 63, wave = tid >> 6;
  const int wm = wave >> 1, wn = wave & 1;
  const int lm = lane & 15, kq = lane >> 4;

  f32x4 acc[4][4] = {};
  for (int k0 = 0; k0 < NH; k0 += 32) {
#pragma unroll
    for (int rr = 0; rr < 2; rr++) {
      int c = tid + rr * 256;
      int row = c >> 2, col = (c & 3) * 8;
      gload_lds16(Acat + (size_t)(r0 + row) * NH + k0 + col, (char*)As + c * 16);
      gload_lds16(WiT + (size_t)(c0 + row) * NH + k0 + col, (char*)Bs + c * 16);
    }
    __syncthreads();
    bf16x8 a[4], b[4];
#pragma unroll
    for (int i = 0; i < 4; i++) {
      a[i] = *(const bf16x8*)&As[(wm * 64 + i * 16 + lm) * 32 + kq * 8];
      b[i] = *(const bf16x8*)&Bs[(wn * 64 + i * 16 + lm) * 32 + kq * 8];
    }
#pragma unroll
    for (int i = 0; i < 4; i++)
#pragma unroll
      for (int jn = 0; jn < 4; jn++)
        acc[i][jn] = __builtin_amdgcn_mfma_f32_16x16x32_bf16(a[i], b[jn], acc[i][jn], 0, 0, 0);
    __syncthreads();
  }
#pragma unroll
  for (int i = 0; i < 4; i++) {
    int grb = r0 + wm * 64 + i * 16 + kq * 4;
#pragma unroll
    for (int jn = 0; jn < 4; jn++) {
      int gc = c0 + wn * 64 + jn * 16 + lm;
#pragma unroll
      for (int j = 0; j < 4; j++) {
        int g = grb + j;
        size_t dst = (g < NH) ? ((size_t)g * 512 + gc)
                              : ((size_t)(g - NH) * 512 + 256 + gc);
        Wab2[dst] = f2bf(acc[i][jn][j]);
      }
    }
  }
}

// ---- fusedP: round-4 double-buffered skeleton + counted-vmcnt pipeline (T3/T4) + T5 + T1 ----
// accX = IN_t*Wi^T (K=256); accC = IN_t*Wa^T + IN_prev*Wb^T (K=512);
// H = 0.98*(accX+bi) + 0.02*relu(accC + b1 [+ b2 if t!=0]) -> out0 f32
__global__ __launch_bounds__(256) void fusedP(const u16* __restrict__ INz,
                                              const u16* __restrict__ Wab2,
                                              const u16* __restrict__ Wib,
                                              const float* __restrict__ bi,
                                              const float* __restrict__ bias1,
                                              const float* __restrict__ bias2,
                                              float* __restrict__ out0) {
  __shared__ __align__(16) u16 As[2][128 * 32];
  __shared__ __align__(16) u16 Bs[2][128 * 32];
  __shared__ __align__(16) u16 Bs2[2][128 * 32];
  const int tid = threadIdx.x;
  // T1: XCD-aware swizzle. 2048 blocks, 8 XCDs -> each XCD gets 256 contiguous
  // swz values = 32 r-tiles x 8 c-tiles (its INz slice 2.1 MB fits a 4 MB L2).
  const int bid = blockIdx.x;
  const int s = (bid & 7) * 256 + (bid >> 3);
  const int r0 = (s >> 3) * 128, c0 = (s & 7) * 128;
  const int lane = tid & 63, wave = tid >> 6;
  const int wm = wave >> 1, wn = wave & 1;
  const int lm = lane & 15, kq = lane >> 4;

  // staging address pieces (constant across iters)
  const int c1 = tid, c2 = tid + 256;
  const int row1 = c1 >> 2, col1 = (c1 & 3) * 8;
  const int row2 = c2 >> 2, col2 = (c2 & 3) * 8;
  const int ra1 = r0 + row1, ra2 = r0 + row2;
  const int pz1 = ((ra1 & (T_LEN - 1)) == 0) ? 0 : ra1;
  const int pz2 = ((ra2 & (T_LEN - 1)) == 0) ? 0 : ra2;

#define STAGE_AB1(buf, k0)                                                        \
  {                                                                               \
    gload_lds16(INz + (size_t)(ra1 + 1) * NIN + (k0) + col1,                      \
                (char*)As[buf] + c1 * 16);                                        \
    gload_lds16(INz + (size_t)(ra2 + 1) * NIN + (k0) + col2,                      \
                (char*)As[buf] + c2 * 16);                                        \
    gload_lds16(Wab2 + (size_t)(c0 + row1) * 512 + (k0) + col1,                   \
                (char*)Bs[buf] + c1 * 16);                                        \
    gload_lds16(Wab2 + (size_t)(c0 + row2) * 512 + (k0) + col2,                   \
                (char*)Bs[buf] + c2 * 16);                                        \
  }
#define STAGE_AB2(buf, k0)                                                        \
  {                                                                               \
    gload_lds16(INz + (size_t)pz1 * NIN + ((k0) - 256) + col1,                    \
                (char*)As[buf] + c1 * 16);                                        \
    gload_lds16(INz + (size_t)pz2 * NIN + ((k0) - 256) + col2,                    \
                (char*)As[buf] + c2 * 16);                                        \
    gload_lds16(Wab2 + (size_t)(c0 + row1) * 512 + (k0) + col1,                   \
                (char*)Bs[buf] + c1 * 16);                                        \
    gload_lds16(Wab2 + (size_t)(c0 + row2) * 512 + (k0) + col2,                   \
                (char*)Bs[buf] + c2 * 16);                                        \
  }
#define STAGE_B2(buf, k0)                                                         \
  {                                                                               \
    gload_lds16(Wib + (size_t)(c0 + row1) * NIN + (k0) + col1,                    \
                (char*)Bs2[buf] + c1 * 16);                                       \
    gload_lds16(Wib + (size_t)(c0 + row2) * NIN + (k0) + col2,                    \
                (char*)Bs2[buf] + c2 * 16);                                       \
  }
  // counted waits: stage(t+1) stays in flight across the barrier; wait only for
  // stage(t) (= all-but-the-N-newest loads). Never vmcnt(0) in the loop body.
#define WAITV6 asm volatile("s_waitcnt vmcnt(6)" ::: "memory")
#define WAITV4 asm volatile("s_waitcnt vmcnt(4)" ::: "memory")
#define WAITV0 asm volatile("s_waitcnt vmcnt(0)" ::: "memory")
#define WAITL0                                                                    \
  {                                                                               \
    asm volatile("s_waitcnt lgkmcnt(0)" ::: "memory");                            \
    __builtin_amdgcn_sched_barrier(0);                                            \
  }

  f32x4 accC[4][4] = {};
  f32x4 accX[4][4] = {};

  // prologue: stage tile 0
  STAGE_AB1(0, 0);
  STAGE_B2(0, 0);
  int cur = 0;

  // ---- phase 1: k0 = 0..224, both GEMMs (6-load stages) ----
#pragma unroll
  for (int it = 0; it < 8; ++it) {
    if (it < 7) {
      STAGE_AB1(cur ^ 1, (it + 1) * 32);
      STAGE_B2(cur ^ 1, (it + 1) * 32);
      WAITV6;
    } else {
      STAGE_AB2(cur ^ 1, 256);  // first phase-2 tile, 4 loads
      WAITV4;
    }
    __builtin_amdgcn_s_barrier();     // buf[cur] ready for all waves
    bf16x8 a[4], b[4], b2[4];
#pragma unroll
    for (int i = 0; i < 4; i++) {
      a[i]  = *(const bf16x8*)&As[cur][(wm * 64 + i * 16 + lm) * 32 + kq * 8];
      b[i]  = *(const bf16x8*)&Bs[cur][(wn * 64 + i * 16 + lm) * 32 + kq * 8];
      b2[i] = *(const bf16x8*)&Bs2[cur][(wn * 64 + i * 16 + lm) * 32 + kq * 8];
    }
    WAITL0;
    __builtin_amdgcn_s_setprio(1);
#pragma unroll
    for (int i = 0; i < 4; i++)
#pragma unroll
      for (int jn = 0; jn < 4; jn++) {
        accC[i][jn] = __builtin_amdgcn_mfma_f32_16x16x32_bf16(a[i], b[jn], accC[i][jn], 0, 0, 0);
        accX[i][jn] = __builtin_amdgcn_mfma_f32_16x16x32_bf16(a[i], b2[jn], accX[i][jn], 0, 0, 0);
      }
    __builtin_amdgcn_s_setprio(0);
    __builtin_amdgcn_s_barrier();     // all waves done reading buf[cur]
    cur ^= 1;
  }
  // ---- phase 2: k0 = 256..480, accC only (4-load stages) ----
#pragma unroll
  for (int it = 8; it < 16; ++it) {
    if (it < 15) {
      STAGE_AB2(cur ^ 1, (it + 1) * 32);
      WAITV4;
    } else {
      WAITV0;                          // last tile: nothing newer in flight
    }
    __builtin_amdgcn_s_barrier();
    bf16x8 a[4], b[4];
#pragma unroll
    for (int i = 0; i < 4; i++) {
      a[i] = *(const bf16x8*)&As[cur][(wm * 64 + i * 16 + lm) * 32 + kq * 8];
      b[i] = *(const bf16x8*)&Bs[cur][(wn * 64 + i * 16 + lm) * 32 + kq * 8];
    }
    WAITL0;
    __builtin_amdgcn_s_setprio(1);
#pragma unroll
    for (int i = 0; i < 4; i++)
#pragma unroll
      for (int jn = 0; jn < 4; jn++)
        accC[i][jn] = __builtin_amdgcn_mfma_f32_16x16x32_bf16(a[i], b[jn], accC[i][jn], 0, 0, 0);
    __builtin_amdgcn_s_setprio(0);
    __builtin_amdgcn_s_barrier();
    cur ^= 1;
  }
#undef STAGE_AB1
#undef STAGE_AB2
#undef STAGE_B2

#pragma unroll
  for (int i = 0; i < 4; i++) {
    int grb = r0 + wm * 64 + i * 16 + kq * 4;
#pragma unroll
    for (int jn = 0; jn < 4; jn++) {
      int gc = c0 + wn * 64 + jn * 16 + lm;
      float b1 = bias1[gc], b2v = bias2[gc], biv = bi[gc];
#pragma unroll
      for (int j = 0; j < 4; j++) {
        int gr = grb + j;
        float bb = b1 + (((gr & (T_LEN - 1)) != 0) ? b2v : 0.0f);
        float cv = fmaxf(accC[i][jn][j] + bb, 0.0f);
        float x = accX[i][jn][j] + biv;
        out0[(size_t)gr * NH + gc] = 0.98f * x + 0.02f * cv;
      }
    }
  }
}

// ---------------- GEMM3: OUT = H * Wo^T + bo  (A reg-staged f32->bf16) ----------------
__global__ __launch_bounds__(256) void gemm3(const float* __restrict__ H,
                                             const u16* __restrict__ Wob,
                                             const float* __restrict__ bo,
                                             float* __restrict__ out1) {
  __shared__ __align__(16) u16 As[128 * 32];
  __shared__ __align__(16) u16 Bs[128 * 32];
  const int tid = threadIdx.x;
  const int r0 = blockIdx.x * 128, c0 = blockIdx.y * 128;
  const int lane = tid & 63, wave = tid >> 6;
  const int wm = wave >> 1, wn = wave & 1;
  const int lm = lane & 15, kq = lane >> 4;

  f32x4 acc[4][4] = {};
  for (int k0 = 0; k0 < NH; k0 += 32) {
#pragma unroll
    for (int rr = 0; rr < 2; rr++) {
      int c = tid + rr * 256;
      int row = c >> 2, col = (c & 3) * 8;
      const float* src = H + (size_t)(r0 + row) * NH + k0 + col;
      float4 v0 = *(const float4*)src;
      float4 v1 = *(const float4*)(src + 4);
      union { u16 u[8]; uint4 q; } pk;
      pk.u[0] = f2bf(v0.x); pk.u[1] = f2bf(v0.y); pk.u[2] = f2bf(v0.z); pk.u[3] = f2bf(v0.w);
      pk.u[4] = f2bf(v1.x); pk.u[5] = f2bf(v1.y); pk.u[6] = f2bf(v1.z); pk.u[7] = f2bf(v1.w);
      *(uint4*)((char*)As + c * 16) = pk.q;
      gload_lds16(Wob + (size_t)(c0 + row) * NH + k0 + col, (char*)Bs + c * 16);
    }
    __syncthreads();
    bf16x8 a[4], b[4];
#pragma unroll
    for (int i = 0; i < 4; i++) {
      a[i] = *(const bf16x8*)&As[(wm * 64 + i * 16 + lm) * 32 + kq * 8];
      b[i] = *(const bf16x8*)&Bs[(wn * 64 + i * 16 + lm) * 32 + kq * 8];
    }
#pragma unroll
    for (int i = 0; i < 4; i++)
#pragma unroll
      for (int jn = 0; jn < 4; jn++)
        acc[i][jn] = __builtin_amdgcn_mfma_f32_16x16x32_bf16(a[i], b[jn], acc[i][jn], 0, 0, 0);
    __syncthreads();
  }
#pragma unroll
  for (int i = 0; i < 4; i++) {
    int grb = r0 + wm * 64 + i * 16 + kq * 4;
#pragma unroll
    for (int jn = 0; jn < 4; jn++) {
      int gc = c0 + wn * 64 + jn * 16 + lm;
      float bv = bo[gc];
#pragma unroll
      for (int j = 0; j < 4; j++)
        out1[(size_t)(grb + j) * NOUT + gc] = acc[i][jn][j] + bv;
    }
  }
}

extern "C" void kernel_launch(void* const* d_in, const int* in_sizes, int n_in,
                              void* d_out, int out_size, void* d_ws, size_t ws_size,
                              hipStream_t stream) {
  const float* inp = (const float*)d_in[0];
  const float* Wi  = (const float*)d_in[1];
  const float* bi  = (const float*)d_in[2];
  const float* Wih = (const float*)d_in[3];
  const float* bih = (const float*)d_in[4];
  const float* Whh = (const float*)d_in[5];
  const float* bhh = (const float*)d_in[6];
  const float* Wo  = (const float*)d_in[7];
  const float* bo  = (const float*)d_in[8];

  float* out0 = (float*)d_out;                       // hidden [32768,1024] f32
  float* out1 = out0 + (size_t)M_TOT * NH;           // output [32768,256]  f32

  char* ws = (char*)d_ws;
  u16* Acat = (u16*)ws;                              //  2048 x 1024 bf16 =  4,194,304 B
  u16* WiT  = (u16*)(ws + 4194304);                  //   256 x 1024 bf16 =    524,288 B
  u16* Wab2 = (u16*)(ws + 4718592);                  //  1024 x  512 bf16 =  1,048,576 B
  u16* Wib  = (u16*)(ws + 5767168);                  //  1024 x  256 bf16 =    524,288 B
  u16* Wob  = (u16*)(ws + 6291456);                  //   256 x 1024 bf16 =    524,288 B
  float* bias1 = (float*)(ws + 6815744);             //  1024 f32 = 4096 B
  float* bias2 = (float*)(ws + 6819840);             //  1024 f32 = 4096 B
  // total ws usage: 6,823,936 B
  // INz lives in the out1 region (33.5 MB >= 16.8 MB); dead before gemm3 writes out1.
  u16* INz = (u16*)out1;                             // [1+32768][256] bf16 = 16,777,728 B

  hipLaunchKernelGGL(prep, dim3(2048), dim3(256), 0, stream,
                     inp, Wi, Wih, Whh, Wo, INz, WiT, Acat, Wib, Wob);
  hipLaunchKernelGGL(wab, dim3(16, 2), dim3(256), 0, stream, Acat, WiT, Wab2);
  hipLaunchKernelGGL(biasvec, dim3(1024), dim3(256), 0, stream,
                     Wih, Whh, bi, bih, bhh, bias1, bias2);
  hipLaunchKernelGGL(fusedP, dim3(2048), dim3(256), 0, stream,
                     INz, Wab2, Wib, bi, bias1, bias2, out0);
  hipLaunchKernelGGL(gemm3, dim3(256, 2), dim3(256), 0, stream, out0, Wob, bo, out1);
}

// Round 7
// 149.613 us; speedup vs baseline: 1.5382x; 1.0458x over previous
//
#include <hip/hip_runtime.h>

#define M_TOT 32768   // B*T = 64*512
#define T_LEN 512
#define NIN   256
#define NH    1024
#define NOUT  256

typedef __attribute__((ext_vector_type(8))) short bf16x8;
typedef __attribute__((ext_vector_type(4))) float f32x4;
typedef unsigned short u16;
typedef unsigned int u32;

__device__ inline float bf2f(u16 u) {
  union { float f; unsigned int i; } v; v.i = ((unsigned int)u) << 16; return v.f;
}
__device__ inline u16 f2bf(float f) {
  union { float f; unsigned int i; } v; v.f = f;
  unsigned int r = v.i + 0x7FFFu + ((v.i >> 16) & 1u);
  return (u16)(r >> 16);
}

__device__ inline void gload_lds16(const void* g, void* l) {
  __builtin_amdgcn_global_load_lds(
      (const __attribute__((address_space(1))) void*)g,
      (__attribute__((address_space(3))) void*)l, 16, 0, 0);
}

// ---------------- prep: bf16 conversions, WiT transpose, Acat build, zero row ----------------
// INz layout: row 0 = zeros (256), row r>=1 = IN row r-1.  [32769][256] bf16
__global__ void prep(const float* __restrict__ inp, const float* __restrict__ Wi,
                     const float* __restrict__ Wih, const float* __restrict__ Whh,
                     const float* __restrict__ Wo,
                     u16* __restrict__ INz, u16* __restrict__ WiT,
                     u16* __restrict__ Acat, u16* __restrict__ Wib, u16* __restrict__ Wob) {
  const long nINz = 256L + (long)M_TOT * NIN;   // 8,388,864
  const long nWiT = 256L * NH;                  // 262,144
  const long nAc  = 2048L * NH;                 // 2,097,152
  const long nWi  = (long)NH * NIN;             // 262,144
  const long nWo  = (long)NOUT * NH;            // 262,144
  const long total = nINz + nWiT + nAc + nWi + nWo;
  for (long i = (long)blockIdx.x * blockDim.x + threadIdx.x; i < total;
       i += (long)gridDim.x * blockDim.x) {
    long j = i;
    if (j < nINz) { INz[j] = (j < 256) ? (u16)0 : f2bf(inp[j - 256]); continue; }
    j -= nINz;
    if (j < nWiT) {  // WiT[it][h] = Wi[h][it]
      long it = j >> 10, h = j & 1023;
      WiT[j] = f2bf(Wi[h * NIN + it]);
      continue;
    }
    j -= nWiT;
    if (j < nAc) {   // Acat = [W_ih ; 0.98*W_hh]  (2048 x 1024)
      long g = j >> 10, h = j & 1023;
      Acat[j] = (g < NH) ? f2bf(Wih[g * NH + h])
                         : f2bf(0.98f * Whh[(g - NH) * NH + h]);
      continue;
    }
    j -= nAc;
    if (j < nWi) { Wib[j] = f2bf(Wi[j]); continue; }
    j -= nWi;
    Wob[j] = f2bf(Wo[j]);
  }
}

// ---------------- biasvec: b1[g]=bih+bhh+W_ih.bi ; b2[g]=0.98*W_hh.bi ----------------
__global__ __launch_bounds__(256) void biasvec(const float* __restrict__ Wih,
                                               const float* __restrict__ Whh,
                                               const float* __restrict__ bi,
                                               const float* __restrict__ bih,
                                               const float* __restrict__ bhh,
                                               float* __restrict__ bias1,
                                               float* __restrict__ bias2) {
  __shared__ float s1[256], s2[256];
  const int g = blockIdx.x, tid = threadIdx.x;
  float a1 = 0.f, a2 = 0.f;
#pragma unroll
  for (int q = 0; q < 4; q++) {
    int h = tid + q * 256;
    float bv = bi[h];
    a1 += Wih[(size_t)g * NH + h] * bv;
    a2 += Whh[(size_t)g * NH + h] * bv;
  }
  s1[tid] = a1; s2[tid] = a2;
  __syncthreads();
  for (int off = 128; off > 0; off >>= 1) {
    if (tid < off) { s1[tid] += s1[tid + off]; s2[tid] += s2[tid + off]; }
    __syncthreads();
  }
  if (tid == 0) {
    bias1[g] = s1[0] + bih[g] + bhh[g];
    bias2[g] = 0.98f * s2[0];
  }
}

// ---------------- wab: Wab2 = [Wa | Wb] folded weights, M=2048,N=256,K=1024 ----------------
__global__ __launch_bounds__(256) void wab(const u16* __restrict__ Acat,
                                           const u16* __restrict__ WiT,
                                           u16* __restrict__ Wab2) {
  __shared__ __align__(16) u16 As[128 * 32];
  __shared__ __align__(16) u16 Bs[128 * 32];
  const int tid = threadIdx.x;
  const int r0 = blockIdx.x * 128, c0 = blockIdx.y * 128;
  const int lane = tid & 63, wave = tid >> 6;
  const int wm = wave >> 1, wn = wave & 1;
  const int lm = lane & 15, kq = lane >> 4;

  f32x4 acc[4][4] = {};
  for (int k0 = 0; k0 < NH; k0 += 32) {
#pragma unroll
    for (int rr = 0; rr < 2; rr++) {
      int c = tid + rr * 256;
      int row = c >> 2, col = (c & 3) * 8;
      gload_lds16(Acat + (size_t)(r0 + row) * NH + k0 + col, (char*)As + c * 16);
      gload_lds16(WiT + (size_t)(c0 + row) * NH + k0 + col, (char*)Bs + c * 16);
    }
    __syncthreads();
    bf16x8 a[4], b[4];
#pragma unroll
    for (int i = 0; i < 4; i++) {
      a[i] = *(const bf16x8*)&As[(wm * 64 + i * 16 + lm) * 32 + kq * 8];
      b[i] = *(const bf16x8*)&Bs[(wn * 64 + i * 16 + lm) * 32 + kq * 8];
    }
#pragma unroll
    for (int i = 0; i < 4; i++)
#pragma unroll
      for (int jn = 0; jn < 4; jn++)
        acc[i][jn] = __builtin_amdgcn_mfma_f32_16x16x32_bf16(a[i], b[jn], acc[i][jn], 0, 0, 0);
    __syncthreads();
  }
#pragma unroll
  for (int i = 0; i < 4; i++) {
    int grb = r0 + wm * 64 + i * 16 + kq * 4;
#pragma unroll
    for (int jn = 0; jn < 4; jn++) {
      int gc = c0 + wn * 64 + jn * 16 + lm;
#pragma unroll
      for (int j = 0; j < 4; j++) {
        int g = grb + j;
        size_t dst = (g < NH) ? ((size_t)g * 512 + gc)
                              : ((size_t)(g - NH) * 512 + 256 + gc);
        Wab2[dst] = f2bf(acc[i][jn][j]);
      }
    }
  }
}

// ---- fused8: 8-wave 256x128 tile, BK=64, 4-phase/K-tile deep pipeline ----
// accX = IN_t*Wi^T (K=256); accC = IN_t*Wa^T + IN_prev*Wb^T (K=512);
// H = 0.98*(accX+bi) + 0.02*relu(accC + b1 [+ b2 if t!=0]) -> out0 f32
// LDS rows are 128B: XOR-swizzle chunk^=(row&7); linear gload_lds dest +
// inverse-swizzled GLOBAL source (rule 21); swizzled ds_read. 2 barriers +
// one vmcnt(2) per K-tile; stage of tile t+2 issued between them.
__global__ __launch_bounds__(512, 2) void fused8(const u16* __restrict__ INz,
                                                 const u16* __restrict__ Wab2,
                                                 const u16* __restrict__ Wib,
                                                 const float* __restrict__ bi,
                                                 const float* __restrict__ bias1,
                                                 const float* __restrict__ bias2,
                                                 float* __restrict__ out0) {
  __shared__ __align__(16) u16 As[2][256 * 64];   // 2 x 32 KB
  __shared__ __align__(16) u16 Bs[2][128 * 64];   // 2 x 16 KB
  __shared__ __align__(16) u16 B2s[2][128 * 64];  // 2 x 16 KB   (total 128 KB)
  const int tid = threadIdx.x;
  // bijective XCD swizzle over 1024 blocks (128 per XCD)
  const int bid = blockIdx.x;
  const int s = (bid & 7) * 128 + (bid >> 3);
  const int r0 = (s >> 3) * 256, c0 = (s & 7) * 128;
  const int wave = tid >> 6, lane = tid & 63;
  const int wr = wave >> 1, wc = wave & 1;         // 4M x 2N wave grid
  const int lm = lane & 15, kq = lane >> 4;

  // ---- stage geometry: A = 2048 16B-chunks (4/thread), B/B2 = 1024 (2/thread)
  const u16* aT[4]; const u16* aP[4]; u32 aD[4];
#pragma unroll
  for (int i = 0; i < 4; i++) {
    int C = i * 512 + tid, r = C >> 3, p = C & 7, l = p ^ (r & 7);
    aD[i] = (u32)C * 16;
    aT[i] = INz + (size_t)(r0 + r + 1) * NIN + l * 8;   // IN_t source
    int pr = r0 + r;
    int pz = ((pr & (T_LEN - 1)) == 0) ? 0 : pr;
    aP[i] = INz + (size_t)pz * NIN + l * 8;             // IN_prev source
  }
  const u16* bS[2]; const u16* cS[2]; u32 bD[2];
#pragma unroll
  for (int i = 0; i < 2; i++) {
    int C = i * 512 + tid, r = C >> 3, p = C & 7, l = p ^ (r & 7);
    bD[i] = (u32)C * 16;
    bS[i] = Wab2 + (size_t)(c0 + r) * 512 + l * 8;
    cS[i] = Wib + (size_t)(c0 + r) * NIN + l * 8;
  }

#define IS_A(bufi, i, KT)                                                         \
  gload_lds16(((KT) < 4) ? (aT[i] + (KT) * 64) : (aP[i] + ((KT) - 4) * 64),       \
              (char*)&As[bufi][0] + aD[i])
#define IS_B(bufi, i, KT) gload_lds16(bS[i] + (KT) * 64, (char*)&Bs[bufi][0] + bD[i])
#define IS_C(bufi, i, KT) gload_lds16(cS[i] + (KT) * 64, (char*)&B2s[bufi][0] + bD[i])

#define WAITV2 asm volatile("s_waitcnt vmcnt(2)" ::: "memory")
#define WAITV0 asm volatile("s_waitcnt vmcnt(0)" ::: "memory")
#define WAITL0                                                                    \
  {                                                                               \
    asm volatile("s_waitcnt lgkmcnt(0)" ::: "memory");                            \
    __builtin_amdgcn_sched_barrier(0);                                            \
  }

#define PHASE_BODY(nf)                                                            \
  {                                                                               \
    int rowb = wc * 64 + (nf) * 16 + lm;                                          \
    bf16x8 bf0 = *(const bf16x8*)((const char*)&Bs[cur][0] + rowb * 128 +         \
                                  ((kq ^ (lm & 7)) * 16));                        \
    bf16x8 bf1 = *(const bf16x8*)((const char*)&Bs[cur][0] + rowb * 128 +         \
                                  (((4 + kq) ^ (lm & 7)) * 16));                  \
    bf16x8 cf0 = {}, cf1 = {};                                                    \
    if (t < 4) {                                                                  \
      cf0 = *(const bf16x8*)((const char*)&B2s[cur][0] + rowb * 128 +             \
                             ((kq ^ (lm & 7)) * 16));                             \
      cf1 = *(const bf16x8*)((const char*)&B2s[cur][0] + rowb * 128 +             \
                             (((4 + kq) ^ (lm & 7)) * 16));                       \
    }                                                                             \
    WAITL0;                                                                       \
    __builtin_amdgcn_s_setprio(1);                                                \
    _Pragma("unroll") for (int mf = 0; mf < 4; mf++) {                            \
      accC[mf][nf] = __builtin_amdgcn_mfma_f32_16x16x32_bf16(afr[mf][0], bf0,     \
                                                             accC[mf][nf], 0, 0, 0); \
      accC[mf][nf] = __builtin_amdgcn_mfma_f32_16x16x32_bf16(afr[mf][1], bf1,     \
                                                             accC[mf][nf], 0, 0, 0); \
    }                                                                             \
    if (t < 4) {                                                                  \
      _Pragma("unroll") for (int mf = 0; mf < 4; mf++) {                          \
        accX[mf][nf] = __builtin_amdgcn_mfma_f32_16x16x32_bf16(afr[mf][0], cf0,   \
                                                               accX[mf][nf], 0, 0, 0); \
        accX[mf][nf] = __builtin_amdgcn_mfma_f32_16x16x32_bf16(afr[mf][1], cf1,   \
                                                               accX[mf][nf], 0, 0, 0); \
      }                                                                           \
    }                                                                             \
    __builtin_amdgcn_s_setprio(0);                                                \
  }

  f32x4 accC[4][4] = {};
  f32x4 accX[4][4] = {};

  // ---- prologue: full L0 -> buf0, first A-chunk pair of L1 -> buf1, counted wait
  IS_A(0, 0, 0); IS_A(0, 1, 0); IS_A(0, 2, 0); IS_A(0, 3, 0);
  IS_B(0, 0, 0); IS_B(0, 1, 0);
  IS_C(0, 0, 0); IS_C(0, 1, 0);
  IS_A(1, 0, 1); IS_A(1, 1, 1);
  WAITV2;
  __builtin_amdgcn_s_barrier();

  int cur = 0;
#pragma unroll
  for (int t = 0; t < 8; t++) {
    bf16x8 afr[4][2];
    // ---- phase 0: A-stage rest of L(t+1); read all a-frags + nf=0 ----
    if (t < 7) { IS_A(cur ^ 1, 2, t + 1); IS_A(cur ^ 1, 3, t + 1); }
#pragma unroll
    for (int mf = 0; mf < 4; mf++)
#pragma unroll
      for (int ks = 0; ks < 2; ks++) {
        int row = wr * 64 + mf * 16 + lm;
        int phys = (ks * 4 + kq) ^ (lm & 7);
        afr[mf][ks] = *(const bf16x8*)((const char*)&As[cur][0] + row * 128 + phys * 16);
      }
    PHASE_BODY(0)
    // ---- phase 1 ----
    if (t < 7) { IS_B(cur ^ 1, 0, t + 1); IS_B(cur ^ 1, 1, t + 1); }
    PHASE_BODY(1)
    // ---- phase 2 ----
    if (t < 3) { IS_C(cur ^ 1, 0, t + 1); IS_C(cur ^ 1, 1, t + 1); }
    PHASE_BODY(2)
    // ---- phase 3 ----
    PHASE_BODY(3)
    // ---- boundary: B1 (done reading buf[cur]); early A-stage of L(t+2) into
    // the just-freed buf[cur]; counted wait for L(t+1); B2 ----
    __builtin_amdgcn_s_barrier();
    if (t < 6) {
      IS_A(cur, 0, t + 2); IS_A(cur, 1, t + 2);
      WAITV2;
    } else if (t == 6) {
      WAITV0;
    }
    if (t < 7) __builtin_amdgcn_s_barrier();
    cur ^= 1;
  }
#undef IS_A
#undef IS_B
#undef IS_C
#undef PHASE_BODY

  // ---- epilogue ----
#pragma unroll
  for (int mf = 0; mf < 4; mf++) {
    int grb = r0 + wr * 64 + mf * 16 + kq * 4;
#pragma unroll
    for (int nf = 0; nf < 4; nf++) {
      int gc = c0 + wc * 64 + nf * 16 + lm;
      float b1 = bias1[gc], b2v = bias2[gc], biv = bi[gc];
#pragma unroll
      for (int j = 0; j < 4; j++) {
        int gr = grb + j;
        float bb = b1 + (((gr & (T_LEN - 1)) != 0) ? b2v : 0.0f);
        float cv = fmaxf(accC[mf][nf][j] + bb, 0.0f);
        float x = accX[mf][nf][j] + biv;
        out0[(size_t)gr * NH + gc] = 0.98f * x + 0.02f * cv;
      }
    }
  }
}

// ---------------- GEMM3: OUT = H * Wo^T + bo  (A reg-staged f32->bf16) ----------------
__global__ __launch_bounds__(256) void gemm3(const float* __restrict__ H,
                                             const u16* __restrict__ Wob,
                                             const float* __restrict__ bo,
                                             float* __restrict__ out1) {
  __shared__ __align__(16) u16 As[128 * 32];
  __shared__ __align__(16) u16 Bs[128 * 32];
  const int tid = threadIdx.x;
  const int r0 = blockIdx.x * 128, c0 = blockIdx.y * 128;
  const int lane = tid & 63, wave = tid >> 6;
  const int wm = wave >> 1, wn = wave & 1;
  const int lm = lane & 15, kq = lane >> 4;

  f32x4 acc[4][4] = {};
  for (int k0 = 0; k0 < NH; k0 += 32) {
#pragma unroll
    for (int rr = 0; rr < 2; rr++) {
      int c = tid + rr * 256;
      int row = c >> 2, col = (c & 3) * 8;
      const float* src = H + (size_t)(r0 + row) * NH + k0 + col;
      float4 v0 = *(const float4*)src;
      float4 v1 = *(const float4*)(src + 4);
      union { u16 u[8]; uint4 q; } pk;
      pk.u[0] = f2bf(v0.x); pk.u[1] = f2bf(v0.y); pk.u[2] = f2bf(v0.z); pk.u[3] = f2bf(v0.w);
      pk.u[4] = f2bf(v1.x); pk.u[5] = f2bf(v1.y); pk.u[6] = f2bf(v1.z); pk.u[7] = f2bf(v1.w);
      *(uint4*)((char*)As + c * 16) = pk.q;
      gload_lds16(Wob + (size_t)(c0 + row) * NH + k0 + col, (char*)Bs + c * 16);
    }
    __syncthreads();
    bf16x8 a[4], b[4];
#pragma unroll
    for (int i = 0; i < 4; i++) {
      a[i] = *(const bf16x8*)&As[(wm * 64 + i * 16 + lm) * 32 + kq * 8];
      b[i] = *(const bf16x8*)&Bs[(wn * 64 + i * 16 + lm) * 32 + kq * 8];
    }
#pragma unroll
    for (int i = 0; i < 4; i++)
#pragma unroll
      for (int jn = 0; jn < 4; jn++)
        acc[i][jn] = __builtin_amdgcn_mfma_f32_16x16x32_bf16(a[i], b[jn], acc[i][jn], 0, 0, 0);
    __syncthreads();
  }
#pragma unroll
  for (int i = 0; i < 4; i++) {
    int grb = r0 + wm * 64 + i * 16 + kq * 4;
#pragma unroll
    for (int jn = 0; jn < 4; jn++) {
      int gc = c0 + wn * 64 + jn * 16 + lm;
      float bv = bo[gc];
#pragma unroll
      for (int j = 0; j < 4; j++)
        out1[(size_t)(grb + j) * NOUT + gc] = acc[i][jn][j] + bv;
    }
  }
}

extern "C" void kernel_launch(void* const* d_in, const int* in_sizes, int n_in,
                              void* d_out, int out_size, void* d_ws, size_t ws_size,
                              hipStream_t stream) {
  const float* inp = (const float*)d_in[0];
  const float* Wi  = (const float*)d_in[1];
  const float* bi  = (const float*)d_in[2];
  const float* Wih = (const float*)d_in[3];
  const float* bih = (const float*)d_in[4];
  const float* Whh = (const float*)d_in[5];
  const float* bhh = (const float*)d_in[6];
  const float* Wo  = (const float*)d_in[7];
  const float* bo  = (const float*)d_in[8];

  float* out0 = (float*)d_out;                       // hidden [32768,1024] f32
  float* out1 = out0 + (size_t)M_TOT * NH;           // output [32768,256]  f32

  char* ws = (char*)d_ws;
  u16* Acat = (u16*)ws;                              //  2048 x 1024 bf16 =  4,194,304 B
  u16* WiT  = (u16*)(ws + 4194304);                  //   256 x 1024 bf16 =    524,288 B
  u16* Wab2 = (u16*)(ws + 4718592);                  //  1024 x  512 bf16 =  1,048,576 B
  u16* Wib  = (u16*)(ws + 5767168);                  //  1024 x  256 bf16 =    524,288 B
  u16* Wob  = (u16*)(ws + 6291456);                  //   256 x 1024 bf16 =    524,288 B
  float* bias1 = (float*)(ws + 6815744);             //  1024 f32 = 4096 B
  float* bias2 = (float*)(ws + 6819840);             //  1024 f32 = 4096 B
  // total ws usage: 6,823,936 B
  // INz lives in the out1 region (33.5 MB >= 16.8 MB); dead before gemm3 writes out1.
  u16* INz = (u16*)out1;                             // [1+32768][256] bf16 = 16,777,728 B

  hipLaunchKernelGGL(prep, dim3(2048), dim3(256), 0, stream,
                     inp, Wi, Wih, Whh, Wo, INz, WiT, Acat, Wib, Wob);
  hipLaunchKernelGGL(wab, dim3(16, 2), dim3(256), 0, stream, Acat, WiT, Wab2);
  hipLaunchKernelGGL(biasvec, dim3(1024), dim3(256), 0, stream,
                     Wih, Whh, bi, bih, bhh, bias1, bias2);
  hipLaunchKernelGGL(fused8, dim3(1024), dim3(512), 0, stream,
                     INz, Wab2, Wib, bi, bias1, bias2, out0);
  hipLaunchKernelGGL(gemm3, dim3(256, 2), dim3(256), 0, stream, out0, Wob, bo, out1);
}

// Round 8
// 139.675 us; speedup vs baseline: 1.6476x; 1.0712x over previous
//
#include <hip/hip_runtime.h>

#define M_TOT 32768   // B*T = 64*512
#define T_LEN 512
#define NIN   256
#define NH    1024
#define NOUT  256

typedef __attribute__((ext_vector_type(8))) short bf16x8;
typedef __attribute__((ext_vector_type(4))) float f32x4;
typedef unsigned short u16;
typedef unsigned int u32;

__device__ inline float bf2f(u16 u) {
  union { float f; unsigned int i; } v; v.i = ((unsigned int)u) << 16; return v.f;
}
__device__ inline u16 f2bf(float f) {
  union { float f; unsigned int i; } v; v.f = f;
  unsigned int r = v.i + 0x7FFFu + ((v.i >> 16) & 1u);
  return (u16)(r >> 16);
}

__device__ inline void gload_lds16(const void* g, void* l) {
  __builtin_amdgcn_global_load_lds(
      (const __attribute__((address_space(1))) void*)g,
      (__attribute__((address_space(3))) void*)l, 16, 0, 0);
}

#define PACK8(pk, v0, v1, SC)                                                     \
  pk.u[0] = f2bf((SC) * v0.x); pk.u[1] = f2bf((SC) * v0.y);                       \
  pk.u[2] = f2bf((SC) * v0.z); pk.u[3] = f2bf((SC) * v0.w);                       \
  pk.u[4] = f2bf((SC) * v1.x); pk.u[5] = f2bf((SC) * v1.y);                       \
  pk.u[6] = f2bf((SC) * v1.z); pk.u[7] = f2bf((SC) * v1.w);

// ---------------- prep (vectorized x8): INz, WiT, Acat, Wall[:,512:768], Wob ----------------
// INz: row 0 zeros, row r>=1 = IN row r-1. [32769][256] bf16
// Wall: [1024][768]; cols 512..767 = bf16(Wi); cols 0..511 written later by wab.
__global__ __launch_bounds__(256) void prep(const float* __restrict__ inp,
                                            const float* __restrict__ Wi,
                                            const float* __restrict__ Wih,
                                            const float* __restrict__ Whh,
                                            const float* __restrict__ Wo,
                                            u16* __restrict__ INz, u16* __restrict__ WiT,
                                            u16* __restrict__ Acat, u16* __restrict__ Wall,
                                            u16* __restrict__ Wob) {
  const long gid = (long)blockIdx.x * blockDim.x + threadIdx.x;
  const long stride = (long)gridDim.x * blockDim.x;
  union { u16 u[8]; uint4 q; } pk;
  if (gid < 32) ((uint4*)INz)[gid] = make_uint4(0, 0, 0, 0);
  // INz bulk: 1,048,576 vec8 iters
  const long nv = (long)M_TOT * NIN / 8;
  for (long i = gid; i < nv; i += stride) {
    const float4* s = (const float4*)(inp + i * 8);
    float4 v0 = s[0], v1 = s[1];
    PACK8(pk, v0, v1, 1.0f);
    *(uint4*)(INz + 256 + i * 8) = pk.q;
  }
  // Acat = [W_ih ; 0.98*W_hh]  (2048 x 1024), vec8
  for (long i = gid; i < 2048L * 1024 / 8; i += stride) {
    long j = i * 8, g = j >> 10, h = j & 1023;
    const float* s = (g < NH) ? (Wih + g * NH + h) : (Whh + (g - NH) * NH + h);
    float sc = (g < NH) ? 1.0f : 0.98f;
    float4 v0 = ((const float4*)s)[0], v1 = ((const float4*)s)[1];
    PACK8(pk, v0, v1, sc);
    *(uint4*)(Acat + j) = pk.q;
  }
  // WiT[it][h] = Wi[h][it] (scalar, strided reads)
  for (long i = gid; i < 256L * 1024; i += stride) {
    long it = i >> 10, h = i & 1023;
    WiT[i] = f2bf(Wi[h * NIN + it]);
  }
  // Wall Wi panel: Wall[g][512+k] = bf16(Wi[g][k]), vec8
  for (long i = gid; i < 1024L * 256 / 8; i += stride) {
    long j = i * 8, g = j >> 8, k = j & 255;
    const float* s = Wi + g * NIN + k;
    float4 v0 = ((const float4*)s)[0], v1 = ((const float4*)s)[1];
    PACK8(pk, v0, v1, 1.0f);
    *(uint4*)(Wall + g * 768 + 512 + k) = pk.q;
  }
  // Wob, vec8
  for (long i = gid; i < 256L * 1024 / 8; i += stride) {
    long j = i * 8;
    float4 v0 = ((const float4*)(Wo + j))[0], v1 = ((const float4*)(Wo + j))[1];
    PACK8(pk, v0, v1, 1.0f);
    *(uint4*)(Wob + j) = pk.q;
  }
}

// ---------------- biasvec: b1[g]=bih+bhh+W_ih.bi ; b2[g]=0.98*W_hh.bi ----------------
__global__ __launch_bounds__(256) void biasvec(const float* __restrict__ Wih,
                                               const float* __restrict__ Whh,
                                               const float* __restrict__ bi,
                                               const float* __restrict__ bih,
                                               const float* __restrict__ bhh,
                                               float* __restrict__ bias1,
                                               float* __restrict__ bias2) {
  __shared__ float s1[256], s2[256];
  const int g = blockIdx.x, tid = threadIdx.x;
  float a1 = 0.f, a2 = 0.f;
#pragma unroll
  for (int q = 0; q < 4; q++) {
    int h = tid + q * 256;
    float bv = bi[h];
    a1 += Wih[(size_t)g * NH + h] * bv;
    a2 += Whh[(size_t)g * NH + h] * bv;
  }
  s1[tid] = a1; s2[tid] = a2;
  __syncthreads();
  for (int off = 128; off > 0; off >>= 1) {
    if (tid < off) { s1[tid] += s1[tid + off]; s2[tid] += s2[tid + off]; }
    __syncthreads();
  }
  if (tid == 0) {
    bias1[g] = s1[0] + bih[g] + bhh[g];
    bias2[g] = 0.98f * s2[0];
  }
}

// ---------------- wab: Wall[:,0:512] = [Wa | Wb], M=2048,N=256,K=1024 ----------------
__global__ __launch_bounds__(256) void wab(const u16* __restrict__ Acat,
                                           const u16* __restrict__ WiT,
                                           u16* __restrict__ Wall) {
  __shared__ __align__(16) u16 As[128 * 32];
  __shared__ __align__(16) u16 Bs[128 * 32];
  const int tid = threadIdx.x;
  const int r0 = blockIdx.x * 128, c0 = blockIdx.y * 128;
  const int lane = tid & 63, wave = tid >> 6;
  const int wm = wave >> 1, wn = wave & 1;
  const int lm = lane & 15, kq = lane >> 4;

  f32x4 acc[4][4] = {};
  for (int k0 = 0; k0 < NH; k0 += 32) {
#pragma unroll
    for (int rr = 0; rr < 2; rr++) {
      int c = tid + rr * 256;
      int row = c >> 2, col = (c & 3) * 8;
      gload_lds16(Acat + (size_t)(r0 + row) * NH + k0 + col, (char*)As + c * 16);
      gload_lds16(WiT + (size_t)(c0 + row) * NH + k0 + col, (char*)Bs + c * 16);
    }
    __syncthreads();
    bf16x8 a[4], b[4];
#pragma unroll
    for (int i = 0; i < 4; i++) {
      a[i] = *(const bf16x8*)&As[(wm * 64 + i * 16 + lm) * 32 + kq * 8];
      b[i] = *(const bf16x8*)&Bs[(wn * 64 + i * 16 + lm) * 32 + kq * 8];
    }
#pragma unroll
    for (int i = 0; i < 4; i++)
#pragma unroll
      for (int jn = 0; jn < 4; jn++)
        acc[i][jn] = __builtin_amdgcn_mfma_f32_16x16x32_bf16(a[i], b[jn], acc[i][jn], 0, 0, 0);
    __syncthreads();
  }
#pragma unroll
  for (int i = 0; i < 4; i++) {
    int grb = r0 + wm * 64 + i * 16 + kq * 4;
#pragma unroll
    for (int jn = 0; jn < 4; jn++) {
      int gc = c0 + wn * 64 + jn * 16 + lm;
#pragma unroll
      for (int j = 0; j < 4; j++) {
        int g = grb + j;
        size_t dst = (g < NH) ? ((size_t)g * 768 + gc)
                              : ((size_t)(g - NH) * 768 + 256 + gc);
        Wall[dst] = f2bf(acc[i][jn][j]);
      }
    }
  }
}

// ---- fused12: BM=BN=128, BK=64, 12 uniform K-tiles, single A+B LDS (64 KB, 2 blocks/CU) ----
// tiles 0-3: A=IN_t,   B=Wall[:,0:256]   -> accC  (IN_t*Wa^T)
// tiles 4-7: A=IN_prev,B=Wall[:,256:512] -> accC  (+IN_prev*Wb^T)
// tiles 8-11:A=IN_t,   B=Wall[:,512:768] -> accX  (IN_t*Wi^T)
// Per tile: {stage(t+1) 8 loads; vmcnt(8); barrier; 16 ds_read; lgkm(0); 32 MFMA; barrier}
// H = 0.98*(accX+bi) + 0.02*relu(accC + b1 [+ b2 if t!=0]) -> out0 f32
__global__ __launch_bounds__(256, 2) void fused12(const u16* __restrict__ INz,
                                                  const u16* __restrict__ Wall,
                                                  const float* __restrict__ bi,
                                                  const float* __restrict__ bias1,
                                                  const float* __restrict__ bias2,
                                                  float* __restrict__ out0) {
  __shared__ __align__(16) u16 As[2][128 * 64];   // 2 x 16 KB
  __shared__ __align__(16) u16 Bs[2][128 * 64];   // 2 x 16 KB  (total 64 KB)
  const int tid = threadIdx.x;
  // bijective XCD swizzle over 2048 blocks (256 per XCD)
  const int bid = blockIdx.x;
  const int s = (bid & 7) * 256 + (bid >> 3);
  const int r0 = (s >> 3) * 128, c0 = (s & 7) * 128;
  const int wave = tid >> 6, lane = tid & 63;
  const int wr = wave >> 1, wc = wave & 1;         // 2x2 wave grid, 64x64 out each
  const int lm = lane & 15, kq = lane >> 4;

  // stage geometry: 1024 16B-chunks per panel, 4 per thread (groups i=0..3 of 32 rows).
  // phys chunk C = i*256+tid -> row r = i*32+(tid>>3), phys col p = tid&7,
  // logical k-chunk l = p ^ (r&7)  (r&7 == (tid>>3)&7 since 32%8==0).
  const int rr = tid >> 3;
  const int l = (tid & 7) ^ (rr & 7);
  const u16* aTb = INz + (size_t)(r0 + rr + 1) * NIN + l * 8;   // IN_t, group 0
  const bool bnd = ((r0 & (T_LEN - 1)) == 0) && (rr == 0);
  const u16* aP0 = bnd ? (INz + l * 8) : (aTb - NIN);           // IN_prev, group 0
  const u16* bb = Wall + (size_t)(c0 + rr) * 768 + l * 8;
  const u32 aD = (u32)tid * 16;

#define IS_A(bufi, i, KT)                                                         \
  gload_lds16(((KT) < 4) ? (aTb + (size_t)(i) * 32 * NIN + (KT) * 64)             \
              : (((KT) < 8) ? (((i) == 0 ? aP0 : aTb + (size_t)(i) * 32 * NIN - NIN) \
                               + ((KT) - 4) * 64)                                 \
                            : (aTb + (size_t)(i) * 32 * NIN + ((KT) - 8) * 64)),  \
              (char*)&As[bufi][0] + aD + (i) * 4096)
#define IS_B(bufi, i, KT)                                                         \
  gload_lds16(bb + (size_t)(i) * 32 * 768 + (KT) * 64,                            \
              (char*)&Bs[bufi][0] + aD + (i) * 4096)
#define STAGE(bufi, KT)                                                           \
  {                                                                               \
    IS_A(bufi, 0, KT); IS_A(bufi, 1, KT); IS_A(bufi, 2, KT); IS_A(bufi, 3, KT);   \
    IS_B(bufi, 0, KT); IS_B(bufi, 1, KT); IS_B(bufi, 2, KT); IS_B(bufi, 3, KT);   \
  }
#define WAITV8 asm volatile("s_waitcnt vmcnt(8)" ::: "memory")
#define WAITV0 asm volatile("s_waitcnt vmcnt(0)" ::: "memory")
#define WAITL0                                                                    \
  {                                                                               \
    asm volatile("s_waitcnt lgkmcnt(0)" ::: "memory");                            \
    __builtin_amdgcn_sched_barrier(0);                                            \
  }

  f32x4 accC[4][4] = {};
  f32x4 accX[4][4] = {};

  STAGE(0, 0);

#pragma unroll
  for (int t = 0; t < 12; t++) {
    if (t < 11) { STAGE((t + 1) & 1, t + 1); WAITV8; } else { WAITV0; }
    __builtin_amdgcn_s_barrier();     // buf[t&1] fully staged for all waves
    const char* Ab = (const char*)&As[t & 1][0];
    const char* Bb = (const char*)&Bs[t & 1][0];
    bf16x8 af[4][2], bf[4][2];
#pragma unroll
    for (int mf = 0; mf < 4; mf++)
#pragma unroll
      for (int ks = 0; ks < 2; ks++) {
        int row = wr * 64 + mf * 16 + lm;
        int phys = (ks * 4 + kq) ^ (lm & 7);
        af[mf][ks] = *(const bf16x8*)(Ab + row * 128 + phys * 16);
      }
#pragma unroll
    for (int nf = 0; nf < 4; nf++)
#pragma unroll
      for (int ks = 0; ks < 2; ks++) {
        int row = wc * 64 + nf * 16 + lm;
        int phys = (ks * 4 + kq) ^ (lm & 7);
        bf[nf][ks] = *(const bf16x8*)(Bb + row * 128 + phys * 16);
      }
    WAITL0;
    __builtin_amdgcn_s_setprio(1);
    if (t < 8) {
#pragma unroll
      for (int mf = 0; mf < 4; mf++)
#pragma unroll
        for (int nf = 0; nf < 4; nf++) {
          accC[mf][nf] = __builtin_amdgcn_mfma_f32_16x16x32_bf16(af[mf][0], bf[nf][0], accC[mf][nf], 0, 0, 0);
          accC[mf][nf] = __builtin_amdgcn_mfma_f32_16x16x32_bf16(af[mf][1], bf[nf][1], accC[mf][nf], 0, 0, 0);
        }
    } else {
#pragma unroll
      for (int mf = 0; mf < 4; mf++)
#pragma unroll
        for (int nf = 0; nf < 4; nf++) {
          accX[mf][nf] = __builtin_amdgcn_mfma_f32_16x16x32_bf16(af[mf][0], bf[nf][0], accX[mf][nf], 0, 0, 0);
          accX[mf][nf] = __builtin_amdgcn_mfma_f32_16x16x32_bf16(af[mf][1], bf[nf][1], accX[mf][nf], 0, 0, 0);
        }
    }
    __builtin_amdgcn_s_setprio(0);
    __builtin_amdgcn_s_barrier();     // all waves done reading buf[t&1]
  }
#undef IS_A
#undef IS_B
#undef STAGE

  // ---- epilogue ----
#pragma unroll
  for (int mf = 0; mf < 4; mf++) {
    int grb = r0 + wr * 64 + mf * 16 + kq * 4;
#pragma unroll
    for (int nf = 0; nf < 4; nf++) {
      int gc = c0 + wc * 64 + nf * 16 + lm;
      float b1 = bias1[gc], b2v = bias2[gc], biv = bi[gc];
#pragma unroll
      for (int j = 0; j < 4; j++) {
        int gr = grb + j;
        float bb2 = b1 + (((gr & (T_LEN - 1)) != 0) ? b2v : 0.0f);
        float cv = fmaxf(accC[mf][nf][j] + bb2, 0.0f);
        float x = accX[mf][nf][j] + biv;
        out0[(size_t)gr * NH + gc] = 0.98f * x + 0.02f * cv;
      }
    }
  }
}

// ---------------- GEMM3: OUT = H * Wo^T + bo  (A reg-staged f32->bf16) ----------------
__global__ __launch_bounds__(256) void gemm3(const float* __restrict__ H,
                                             const u16* __restrict__ Wob,
                                             const float* __restrict__ bo,
                                             float* __restrict__ out1) {
  __shared__ __align__(16) u16 As[128 * 32];
  __shared__ __align__(16) u16 Bs[128 * 32];
  const int tid = threadIdx.x;
  const int r0 = blockIdx.x * 128, c0 = blockIdx.y * 128;
  const int lane = tid & 63, wave = tid >> 6;
  const int wm = wave >> 1, wn = wave & 1;
  const int lm = lane & 15, kq = lane >> 4;

  f32x4 acc[4][4] = {};
  for (int k0 = 0; k0 < NH; k0 += 32) {
#pragma unroll
    for (int rr = 0; rr < 2; rr++) {
      int c = tid + rr * 256;
      int row = c >> 2, col = (c & 3) * 8;
      const float* src = H + (size_t)(r0 + row) * NH + k0 + col;
      float4 v0 = *(const float4*)src;
      float4 v1 = *(const float4*)(src + 4);
      union { u16 u[8]; uint4 q; } pk;
      PACK8(pk, v0, v1, 1.0f);
      *(uint4*)((char*)As + c * 16) = pk.q;
      gload_lds16(Wob + (size_t)(c0 + row) * NH + k0 + col, (char*)Bs + c * 16);
    }
    __syncthreads();
    bf16x8 a[4], b[4];
#pragma unroll
    for (int i = 0; i < 4; i++) {
      a[i] = *(const bf16x8*)&As[(wm * 64 + i * 16 + lm) * 32 + kq * 8];
      b[i] = *(const bf16x8*)&Bs[(wn * 64 + i * 16 + lm) * 32 + kq * 8];
    }
#pragma unroll
    for (int i = 0; i < 4; i++)
#pragma unroll
      for (int jn = 0; jn < 4; jn++)
        acc[i][jn] = __builtin_amdgcn_mfma_f32_16x16x32_bf16(a[i], b[jn], acc[i][jn], 0, 0, 0);
    __syncthreads();
  }
#pragma unroll
  for (int i = 0; i < 4; i++) {
    int grb = r0 + wm * 64 + i * 16 + kq * 4;
#pragma unroll
    for (int jn = 0; jn < 4; jn++) {
      int gc = c0 + wn * 64 + jn * 16 + lm;
      float bv = bo[gc];
#pragma unroll
      for (int j = 0; j < 4; j++)
        out1[(size_t)(grb + j) * NOUT + gc] = acc[i][jn][j] + bv;
    }
  }
}

extern "C" void kernel_launch(void* const* d_in, const int* in_sizes, int n_in,
                              void* d_out, int out_size, void* d_ws, size_t ws_size,
                              hipStream_t stream) {
  const float* inp = (const float*)d_in[0];
  const float* Wi  = (const float*)d_in[1];
  const float* bi  = (const float*)d_in[2];
  const float* Wih = (const float*)d_in[3];
  const float* bih = (const float*)d_in[4];
  const float* Whh = (const float*)d_in[5];
  const float* bhh = (const float*)d_in[6];
  const float* Wo  = (const float*)d_in[7];
  const float* bo  = (const float*)d_in[8];

  float* out0 = (float*)d_out;                       // hidden [32768,1024] f32
  float* out1 = out0 + (size_t)M_TOT * NH;           // output [32768,256]  f32

  char* ws = (char*)d_ws;
  u16* Acat = (u16*)ws;                              //  2048 x 1024 bf16 =  4,194,304 B
  u16* WiT  = (u16*)(ws + 4194304);                  //   256 x 1024 bf16 =    524,288 B
  u16* Wall = (u16*)(ws + 4718592);                  //  1024 x  768 bf16 =  1,572,864 B
  u16* Wob  = (u16*)(ws + 6291456);                  //   256 x 1024 bf16 =    524,288 B
  float* bias1 = (float*)(ws + 6815744);             //  1024 f32 = 4096 B
  float* bias2 = (float*)(ws + 6819840);             //  1024 f32 = 4096 B
  // total ws usage: 6,823,936 B
  // INz lives in the out1 region (33.5 MB >= 16.8 MB); dead before gemm3 writes out1.
  u16* INz = (u16*)out1;                             // [1+32768][256] bf16 = 16,777,728 B

  hipLaunchKernelGGL(prep, dim3(2048), dim3(256), 0, stream,
                     inp, Wi, Wih, Whh, Wo, INz, WiT, Acat, Wall, Wob);
  hipLaunchKernelGGL(wab, dim3(16, 2), dim3(256), 0, stream, Acat, WiT, Wall);
  hipLaunchKernelGGL(biasvec, dim3(1024), dim3(256), 0, stream,
                     Wih, Whh, bi, bih, bhh, bias1, bias2);
  hipLaunchKernelGGL(fused12, dim3(2048), dim3(256), 0, stream,
                     INz, Wall, bi, bias1, bias2, out0);
  hipLaunchKernelGGL(gemm3, dim3(256, 2), dim3(256), 0, stream, out0, Wob, bo, out1);
}